// Round 3
// baseline (1287.439 us; speedup 1.0000x reference)
//
#include <hip/hip_runtime.h>
#include <math.h>

// ---------------------------------------------------------------------------
// HDRNet, N=4, low 256x256, full 1024x1024 — single persistent mega-kernel.
// Grid = 1024 blocks x 256 thr, __launch_bounds__(256,4) -> 4 blocks/CU ->
// exactly 1024 co-resident blocks on 256 CUs; phases separated by device-
// scope atomic grid barriers (counters in ws, zeroed via hipMemsetAsync).
// All intermediate buffers are write-once-then-read (no stale-line hazard),
// barriers use __threadfence() release/acquire (G16-safe).
// ---------------------------------------------------------------------------

#define NB 1024
#define GSZ (NB * 256)

__device__ __forceinline__ float tanh_fast(float x) {
    float e = __expf(2.0f * x);
    return 1.0f - 2.0f / (e + 1.0f);
}

__device__ __forceinline__ void gsync(int* bar, int id) {
    __syncthreads();
    if (threadIdx.x == 0) {
        __threadfence();
        int* c = bar + id * 32;                 // 128B-separated counters
        atomicAdd(c, 1);
        int guard = 0;
        while (__hip_atomic_load(c, __ATOMIC_RELAXED, __HIP_MEMORY_SCOPE_AGENT) < NB
               && guard < (1 << 27)) {
            ++guard;
            __builtin_amdgcn_s_sleep(1);
        }
        __threadfence();
    }
    __syncthreads();
}

// thread-per-output 3x3 conv (pad 1), runtime dims
__device__ __forceinline__ float conv_tpo(
    const float* __restrict__ in, const float* __restrict__ w,
    int n, int co, int ho, int wo, int Cin, int Hin, int Win, int stride)
{
    float acc = 0.0f;
    int hi0 = ho * stride - 1, wi0 = wo * stride - 1;
    const float* wp = w + (size_t)co * Cin * 9;
    for (int ci = 0; ci < Cin; ++ci) {
        const float* ip = in + ((size_t)(n * Cin + ci)) * Hin * Win;
        const float* wc = wp + ci * 9;
        #pragma unroll
        for (int kh = 0; kh < 3; ++kh) {
            int hi = hi0 + kh;
            if ((unsigned)hi >= (unsigned)Hin) continue;
            const float* row = ip + hi * Win;
            #pragma unroll
            for (int kw = 0; kw < 3; ++kw) {
                int wi = wi0 + kw;
                if ((unsigned)wi >= (unsigned)Win) continue;
                acc = fmaf(wc[kh * 3 + kw], row[wi], acc);
            }
        }
    }
    return acc;
}

// 4-way input-channel-split 3x3 conv block: 64 outputs per task-block tb
template<int CIN, int STRIDE, bool RELU, bool HASB>
__device__ __forceinline__ void conv_split_tb(
    const float* __restrict__ in, const float* __restrict__ w,
    const float* __restrict__ b, float* __restrict__ out,
    int tb, int Cout, int Hin, int Win, int Hout, int Wout, float* red)
{
    constexpr int CPT = CIN / 4;
    int part = threadIdx.x >> 6;
    int lane = threadIdx.x & 63;
    int o = (tb << 6) | lane;
    int wo = o % Wout; int t = o / Wout;
    int ho = t % Hout; t /= Hout;
    int co = t % Cout; int n = t / Cout;
    int hi0 = ho * STRIDE - 1, wi0 = wo * STRIDE - 1;
    const float* wp = w + ((size_t)co * CIN + part * CPT) * 9;
    const float* ip = in + ((size_t)n * CIN + part * CPT) * Hin * Win;
    float acc = 0.0f;
    for (int ci = 0; ci < CPT; ++ci) {
        const float* ic = ip + (size_t)ci * Hin * Win;
        const float* wc = wp + ci * 9;
        #pragma unroll
        for (int kh = 0; kh < 3; ++kh) {
            int hi = hi0 + kh;
            if ((unsigned)hi >= (unsigned)Hin) continue;
            const float* row = ic + hi * Win;
            #pragma unroll
            for (int kw = 0; kw < 3; ++kw) {
                int wi = wi0 + kw;
                if ((unsigned)wi >= (unsigned)Win) continue;
                acc = fmaf(wc[kh * 3 + kw], row[wi], acc);
            }
        }
    }
    red[threadIdx.x] = acc;
    __syncthreads();
    if (part == 0) {
        float s = acc + red[64 + lane] + red[128 + lane] + red[192 + lane];
        if (HASB) s += b[co];
        if (RELU) s = fmaxf(s, 0.0f);
        out[o] = s;
    }
    __syncthreads();
}

__global__ __launch_bounds__(256, 4) void hdrnet_mega(
    const float* __restrict__ low, const float* __restrict__ full,
    const float* __restrict__ w0, const float* __restrict__ b0,
    const float* __restrict__ w1, const float* __restrict__ b1,
    const float* __restrict__ w2, const float* __restrict__ b2,
    const float* __restrict__ w3, const float* __restrict__ b3,
    const float* __restrict__ wl0, const float* __restrict__ bl0,
    const float* __restrict__ wl1,
    const float* __restrict__ wg1, const float* __restrict__ bg1,
    const float* __restrict__ wg2, const float* __restrict__ bg2,
    const float* __restrict__ wf1, const float* __restrict__ bf1,
    const float* __restrict__ wf2, const float* __restrict__ bf2,
    const float* __restrict__ wf3, const float* __restrict__ bf3,
    const float* __restrict__ wlin, const float* __restrict__ blin,
    const float* __restrict__ wgd1, const float* __restrict__ bgd1,
    const float* __restrict__ wgd2, const float* __restrict__ bgd2,
    const float* __restrict__ wau1, const float* __restrict__ bau1,
    const float* __restrict__ wau2, const float* __restrict__ bau2,
    const float* __restrict__ wav1, const float* __restrict__ bav1,
    const float* __restrict__ wav2, const float* __restrict__ bav2,
    float* __restrict__ out, int* __restrict__ bar, float* __restrict__ wsf)
{
    __shared__ float smem[848];
    float* red = smem;
    const int tid = blockIdx.x * 256 + threadIdx.x;

    float* t0b    = wsf;
    float* t1b    = t0b + 524288;
    float* t2b    = t1b + 262144;
    float* splat  = t2b + 131072;
    float* l0o    = splat + 65536;
    float* localb = l0o + 65536;
    float* x1b    = localb + 65536;
    float* x2b    = x1b + 32768;
    float* avec   = x2b + 16384;
    float* glob   = avec + 1792;
    float* gridb  = glob + 256;

    // ---- P0: conv0  low(4,3,256,256) -> t0(4,8,128,128), 2 outputs/thread
    for (int idx = tid; idx < 524288; idx += GSZ) {
        int wo = idx & 127; int t = idx >> 7;
        int ho = t & 127; t >>= 7;
        int co = t & 7; int n = t >> 3;
        float acc = conv_tpo(low, w0, n, co, ho, wo, 3, 256, 256, 2) + b0[co];
        t0b[idx] = fmaxf(acc, 0.0f);
    }
    gsync(bar, 0);

    // ---- P1: conv1  t0 -> t1(4,16,64,64)
    if (tid < 262144) {
        int wo = tid & 63; int t = tid >> 6;
        int ho = t & 63; t >>= 6;
        int co = t & 15; int n = t >> 4;
        float acc = conv_tpo(t0b, w1, n, co, ho, wo, 8, 128, 128, 2) + b1[co];
        t1b[tid] = fmaxf(acc, 0.0f);
    }
    gsync(bar, 1);

    // ---- P2: conv2  t1 -> t2(4,32,32,32)
    if (tid < 131072) {
        int wo = tid & 31; int t = tid >> 5;
        int ho = t & 31; t >>= 5;
        int co = t & 31; int n = t >> 5;
        float acc = conv_tpo(t1b, w2, n, co, ho, wo, 16, 64, 64, 2) + b2[co];
        t2b[tid] = fmaxf(acc, 0.0f);
    }
    gsync(bar, 2);

    // ---- P3: conv3  t2 -> splat(4,64,16,16), 4-way split, 1024 TBs
    conv_split_tb<32, 2, true, true>(t2b, w3, b3, splat, blockIdx.x, 64, 32, 32, 16, 16, red);
    gsync(bar, 3);

    // ---- P4: l0 (1024 TBs) + g1 (512 TBs)
    for (int tb = blockIdx.x; tb < 1536; tb += NB) {
        if (tb < 1024)
            conv_split_tb<64, 1, true, true>(splat, wl0, bl0, l0o, tb, 64, 16, 16, 16, 16, red);
        else
            conv_split_tb<64, 2, true, true>(splat, wg1, bg1, x1b, tb - 1024, 128, 16, 16, 8, 8, red);
    }
    gsync(bar, 4);

    // ---- P5: l1 (1024 TBs) + g2 (256 TBs)
    for (int tb = blockIdx.x; tb < 1280; tb += NB) {
        if (tb < 1024)
            conv_split_tb<64, 1, false, false>(l0o, wl1, nullptr, localb, tb, 64, 16, 16, 16, 16, red);
        else
            conv_split_tb<128, 2, true, true>(x1b, wg2, bg2, x2b, tb - 1024, 256, 8, 8, 4, 4, red);
    }
    gsync(bar, 5);

    // ---- P6: channel means -> avec[4][448], one wave per mean
    {
        int wid = blockIdx.x * 4 + (threadIdx.x >> 6);
        int lane = threadIdx.x & 63;
        if (wid < 1792) {
            int n = wid / 448; int c = wid % 448;
            float s = 0.0f; float scale;
            if (c < 64) {
                const float* p = splat + ((size_t)(n * 64 + c)) * 256;
                s = p[lane] + p[lane + 64] + p[lane + 128] + p[lane + 192];
                scale = 1.0f / 256.0f;
            } else if (c < 192) {
                const float* p = x1b + ((size_t)(n * 128 + (c - 64))) * 64;
                s = p[lane];
                scale = 1.0f / 64.0f;
            } else {
                const float* p = x2b + ((size_t)(n * 256 + (c - 192))) * 16;
                s = (lane < 16) ? p[lane] : 0.0f;
                scale = 1.0f / 16.0f;
            }
            #pragma unroll
            for (int off = 32; off; off >>= 1) s += __shfl_down(s, off, 64);
            if (lane == 0) avec[wid] = s * scale;
        }
    }
    gsync(bar, 6);

    // ---- P7: FC chain 448->256->128->64, one block per image
    if (blockIdx.x < 4) {
        int n = blockIdx.x, t = threadIdx.x;
        float* a   = smem;        // 448
        float* hh1 = smem + 448;  // 256
        float* hh2 = smem + 704;  // 128
        if (t < 224) { a[t] = avec[n * 448 + t]; a[t + 224] = avec[n * 448 + t + 224]; }
        __syncthreads();
        {
            float a0 = 0, a1 = 0, a2 = 0, a3 = 0;
            const float* wp = wf1 + (size_t)t * 448;
            for (int i = 0; i < 448; i += 4) {
                a0 = fmaf(wp[i], a[i], a0); a1 = fmaf(wp[i + 1], a[i + 1], a1);
                a2 = fmaf(wp[i + 2], a[i + 2], a2); a3 = fmaf(wp[i + 3], a[i + 3], a3);
            }
            float s = a0 + a1 + a2 + a3 + bf1[t];
            __syncthreads();               // a no longer needed after all reads
            hh1[t] = fmaxf(s, 0.0f);
        }
        __syncthreads();
        if (t < 128) {
            float a0 = 0, a1 = 0, a2 = 0, a3 = 0;
            const float* wp = wf2 + (size_t)t * 256;
            for (int i = 0; i < 256; i += 4) {
                a0 = fmaf(wp[i], hh1[i], a0); a1 = fmaf(wp[i + 1], hh1[i + 1], a1);
                a2 = fmaf(wp[i + 2], hh1[i + 2], a2); a3 = fmaf(wp[i + 3], hh1[i + 3], a3);
            }
            hh2[t] = fmaxf(a0 + a1 + a2 + a3 + bf2[t], 0.0f);
        }
        __syncthreads();
        if (t < 64) {
            float a0 = 0, a1 = 0, a2 = 0, a3 = 0;
            const float* wp = wf3 + (size_t)t * 128;
            for (int i = 0; i < 128; i += 4) {
                a0 = fmaf(wp[i], hh2[i], a0); a1 = fmaf(wp[i + 1], hh2[i + 1], a1);
                a2 = fmaf(wp[i + 2], hh2[i + 2], a2); a3 = fmaf(wp[i + 3], hh2[i + 3], a3);
            }
            glob[n * 64 + t] = fmaxf(a0 + a1 + a2 + a3 + bf3[t], 0.0f);
        }
    }
    gsync(bar, 7);

    // ---- P8: fuse + 1x1 -> bilateral grid (channel-innermost layout)
    if (tid < 98304) {
        int p = tid & 255; int k = (tid >> 8) % 96; int n = tid / (96 * 256);
        float acc = blin[k];
        const float* wp = wlin + k * 64;
        const float* gl = glob + n * 64;
        const float* lo = localb + (size_t)n * 64 * 256 + p;
        for (int c = 0; c < 64; ++c)
            acc = fmaf(wp[c], fmaxf(gl[c] + lo[c * 256], 0.0f), acc);
        int ch = k >> 3; int z = k & 7;
        gridb[(((size_t)(n * 8 + z)) * 256 + p) * 12 + ch] = acc;
    }
    gsync(bar, 8);

    // ---- P9: fused full-res output, 4 px/thread, grid-stride x4
    for (int t = tid; t < 1048576; t += GSZ) {
        int x0 = (t & 255) << 2;
        int y = (t >> 8) & 1023;
        int n = t >> 18;
        const float* fp = full + ((size_t)n << 20);

        float v[3][6];
        #pragma unroll
        for (int r = 0; r < 3; ++r) {
            int yy = y + r - 1;
            bool okr = (unsigned)yy < 1024u;
            const float* row = fp + (size_t)yy * 1024;
            if (okr) {
                float4 m = *(const float4*)(row + x0);
                v[r][1] = m.x; v[r][2] = m.y; v[r][3] = m.z; v[r][4] = m.w;
                v[r][0] = (x0 > 0) ? row[x0 - 1] : 0.0f;
                v[r][5] = (x0 < 1020) ? row[x0 + 4] : 0.0f;
            } else {
                #pragma unroll
                for (int j = 0; j < 6; ++j) v[r][j] = 0.0f;
            }
        }

        float gacc[4];
        float bb = bgd2[0];
        #pragma unroll
        for (int px = 0; px < 4; ++px) gacc[px] = bb;
        #pragma unroll
        for (int k = 0; k < 16; ++k) {
            const float* wk = wgd1 + k * 9;
            float q0 = wk[0], q1 = wk[1], q2 = wk[2];
            float q3 = wk[3], q4 = wk[4], q5 = wk[5];
            float q6 = wk[6], q7 = wk[7], q8 = wk[8];
            float bk = bgd1[k], wo = wgd2[k];
            #pragma unroll
            for (int px = 0; px < 4; ++px) {
                float h = bk;
                h = fmaf(q0, v[0][px], h); h = fmaf(q1, v[0][px + 1], h); h = fmaf(q2, v[0][px + 2], h);
                h = fmaf(q3, v[1][px], h); h = fmaf(q4, v[1][px + 1], h); h = fmaf(q5, v[1][px + 2], h);
                h = fmaf(q6, v[2][px], h); h = fmaf(q7, v[2][px + 1], h); h = fmaf(q8, v[2][px + 2], h);
                gacc[px] = fmaf(wo, fmaxf(h, 0.0f), gacc[px]);
            }
        }

        // y-side slice terms (constant over the 4 px)
        float gyc = (y * (32.0f / 1023.0f) - 1.0f) * 0.5f;
        float y0f = floorf(gyc); float fy = gyc - y0f; int iy = (int)y0f;
        float wy0 = (iy >= 0 && iy < 16) ? (1.0f - fy) : 0.0f;
        float wy1 = (iy + 1 < 16) ? fy : 0.0f;
        int yi0 = min(max(iy, 0), 15), yi1 = min(iy + 1, 15);

        // fake-chroma: shared rows/cols for the 4 px
        float sy = (y + 0.5f) * 0.25f - 0.5f;
        float syf = floorf(sy); float fyl = sy - syf;
        int jy0 = max((int)syf, 0), jy1 = min((int)syf + 1, 255);
        int jc = x0 >> 2;
        int c0 = max(jc - 1, 0), c2 = min(jc + 1, 255);
        const float* lr1 = low + ((size_t)(n * 3 + 1)) * 65536;
        const float* lr2 = low + ((size_t)(n * 3 + 2)) * 65536;
        float ua = lr1[jy0 * 256 + c0] + fyl * (lr1[jy1 * 256 + c0] - lr1[jy0 * 256 + c0]);
        float ub = lr1[jy0 * 256 + jc] + fyl * (lr1[jy1 * 256 + jc] - lr1[jy0 * 256 + jc]);
        float uc = lr1[jy0 * 256 + c2] + fyl * (lr1[jy1 * 256 + c2] - lr1[jy0 * 256 + c2]);
        float va = lr2[jy0 * 256 + c0] + fyl * (lr2[jy1 * 256 + c0] - lr2[jy0 * 256 + c0]);
        float vb = lr2[jy0 * 256 + jc] + fyl * (lr2[jy1 * 256 + jc] - lr2[jy0 * 256 + jc]);
        float vc = lr2[jy0 * 256 + c2] + fyl * (lr2[jy1 * 256 + c2] - lr2[jy0 * 256 + c2]);
        const float cfx[4] = {0.625f, 0.875f, 0.125f, 0.375f};

        const float* gbase = gridb + (size_t)n * 24576;
        float Yo[4], Uo[4], Vo[4];

        #pragma unroll
        for (int px = 0; px < 4; ++px) {
            int x = x0 + px;
            float g = tanh_fast(gacc[px]);

            float gxc = (x * (32.0f / 1023.0f) - 1.0f) * 0.5f;
            float gzc = 4.0f * g + 3.5f;
            float x0f = floorf(gxc), z0f = floorf(gzc);
            float fx = gxc - x0f, fz = gzc - z0f;
            int ix = (int)x0f, iz = (int)z0f;

            float wx0 = (ix >= 0 && ix < 16) ? (1.0f - fx) : 0.0f;
            float wx1 = (ix + 1 < 16) ? fx : 0.0f;
            float wz0 = (iz >= 0 && iz < 8) ? (1.0f - fz) : 0.0f;
            float wz1 = (iz + 1 >= 0 && iz + 1 < 8) ? fz : 0.0f;
            int xi0 = min(max(ix, 0), 15), xi1 = min(ix + 1, 15);
            int zi0 = min(max(iz, 0), 7),  zi1 = min(max(iz + 1, 0), 7);

            float w00 = wy0 * wx0, w01 = wy0 * wx1, w10 = wy1 * wx0, w11 = wy1 * wx1;
            int o00 = yi0 * 16 + xi0, o01 = yi0 * 16 + xi1;
            int o10 = yi1 * 16 + xi0, o11 = yi1 * 16 + xi1;
            int z0b = zi0 * 256, z1b = zi1 * 256;

            float acc[12];
            #pragma unroll
            for (int i = 0; i < 12; ++i) acc[i] = 0.0f;

            #define CORNER(OFF, WK) { \
                const float4* q = (const float4*)(gbase + (size_t)(OFF) * 12); \
                float wk_ = (WK); \
                float4 A = q[0], B = q[1], C = q[2]; \
                acc[0] = fmaf(wk_, A.x, acc[0]); acc[1] = fmaf(wk_, A.y, acc[1]); \
                acc[2] = fmaf(wk_, A.z, acc[2]); acc[3] = fmaf(wk_, A.w, acc[3]); \
                acc[4] = fmaf(wk_, B.x, acc[4]); acc[5] = fmaf(wk_, B.y, acc[5]); \
                acc[6] = fmaf(wk_, B.z, acc[6]); acc[7] = fmaf(wk_, B.w, acc[7]); \
                acc[8] = fmaf(wk_, C.x, acc[8]); acc[9] = fmaf(wk_, C.y, acc[9]); \
                acc[10] = fmaf(wk_, C.z, acc[10]); acc[11] = fmaf(wk_, C.w, acc[11]); }

            CORNER(z0b + o00, wz0 * w00)
            CORNER(z0b + o01, wz0 * w01)
            CORNER(z0b + o10, wz0 * w10)
            CORNER(z0b + o11, wz0 * w11)
            CORNER(z1b + o00, wz1 * w00)
            CORNER(z1b + o01, wz1 * w01)
            CORNER(z1b + o10, wz1 * w10)
            CORNER(z1b + o11, wz1 * w11)
            #undef CORNER

            float p = v[1][px + 1];
            float Yv = fmaf(p, acc[3],  acc[0] + acc[1] + acc[2]);
            float U0 = fmaf(p, acc[7],  acc[4] + acc[5] + acc[6]);
            float V0 = fmaf(p, acc[11], acc[8] + acc[9] + acc[10]);

            float uacc = bau2[0];
            #pragma unroll
            for (int k = 0; k < 16; ++k)
                uacc = fmaf(wau2[k], fmaxf(fmaf(wau1[k], U0, bau1[k]), 0.0f), uacc);
            float vacc = bav2[0];
            #pragma unroll
            for (int k = 0; k < 16; ++k)
                vacc = fmaf(wav2[k], fmaxf(fmaf(wav1[k], V0, bav1[k]), 0.0f), vacc);

            float f1 = (px < 2) ? (ua + cfx[px] * (ub - ua)) : (ub + cfx[px] * (uc - ub));
            float f2 = (px < 2) ? (va + cfx[px] * (vb - va)) : (vb + cfx[px] * (vc - vb));

            Yo[px] = Yv;
            Uo[px] = tanh_fast(uacc) + f1;
            Vo[px] = tanh_fast(vacc) + f2;
        }

        size_t base = ((size_t)n * 3) * 1048576 + (size_t)y * 1024 + x0;
        *(float4*)(out + base)            = make_float4(Yo[0], Yo[1], Yo[2], Yo[3]);
        *(float4*)(out + base + 1048576)  = make_float4(Uo[0], Uo[1], Uo[2], Uo[3]);
        *(float4*)(out + base + 2097152)  = make_float4(Vo[0], Vo[1], Vo[2], Vo[3]);
    }
}

extern "C" void kernel_launch(void* const* d_in, const int* in_sizes, int n_in,
                              void* d_out, int out_size, void* d_ws, size_t ws_size,
                              hipStream_t stream)
{
    const float* low  = (const float*)d_in[0];
    const float* full = (const float*)d_in[1];
    const float* w0 = (const float*)d_in[2];  const float* b0 = (const float*)d_in[3];
    const float* w1 = (const float*)d_in[4];  const float* b1 = (const float*)d_in[5];
    const float* w2 = (const float*)d_in[6];  const float* b2 = (const float*)d_in[7];
    const float* w3 = (const float*)d_in[8];  const float* b3 = (const float*)d_in[9];
    const float* wl0 = (const float*)d_in[10]; const float* bl0 = (const float*)d_in[11];
    const float* wl1 = (const float*)d_in[12];
    const float* wg1 = (const float*)d_in[13]; const float* bg1 = (const float*)d_in[14];
    const float* wg2 = (const float*)d_in[15]; const float* bg2 = (const float*)d_in[16];
    const float* wf1 = (const float*)d_in[17]; const float* bf1 = (const float*)d_in[18];
    const float* wf2 = (const float*)d_in[19]; const float* bf2 = (const float*)d_in[20];
    const float* wf3 = (const float*)d_in[21]; const float* bf3 = (const float*)d_in[22];
    const float* wlin = (const float*)d_in[23]; const float* blin = (const float*)d_in[24];
    const float* wgd1 = (const float*)d_in[25]; const float* bgd1 = (const float*)d_in[26];
    const float* wgd2 = (const float*)d_in[27]; const float* bgd2 = (const float*)d_in[28];
    const float* wau1 = (const float*)d_in[29]; const float* bau1 = (const float*)d_in[30];
    const float* wau2 = (const float*)d_in[31]; const float* bau2 = (const float*)d_in[32];
    const float* wav1 = (const float*)d_in[33]; const float* bav1 = (const float*)d_in[34];
    const float* wav2 = (const float*)d_in[35]; const float* bav2 = (const float*)d_in[36];
    float* out = (float*)d_out;

    int* bar = (int*)d_ws;                 // 9 barriers x 32 ints, zeroed below
    float* wsf = (float*)d_ws + 1024;      // data region

    hipMemsetAsync(bar, 0, 4096, stream);
    hdrnet_mega<<<NB, 256, 0, stream>>>(
        low, full, w0, b0, w1, b1, w2, b2, w3, b3, wl0, bl0, wl1,
        wg1, bg1, wg2, bg2, wf1, bf1, wf2, bf2, wf3, bf3, wlin, blin,
        wgd1, bgd1, wgd2, bgd2, wau1, bau1, wau2, bau2, wav1, bav1, wav2, bav2,
        out, bar, wsf);
}

// Round 4
// 394.982 us; speedup vs baseline: 3.2595x; 3.2595x over previous
//
#include <hip/hip_runtime.h>
#include <math.h>

// ---------------------------------------------------------------------------
// HDRNet, N=4, low 256x256, full 1024x1024. Multi-kernel (graph-replayed)
// pipeline — R3's persistent-kernel grid barriers cost ~100us each on 8
// non-coherent XCDs (contended single-line spin at the coherence point);
// reverted to launches. All conv dims templated (pow2 -> shifts, full
// unroll); split-K so every conv launch has >=1024 blocks, <=72 loads/thread.
// Workspace floats: t0 524288 | t1 262144 | t2 131072 | splat 65536 |
// l0o 65536 | local 65536 | x1 32768 | x2 16384 | avec 1792 | glob 256 |
// grid (4,8,16,16,12) 98304
// ---------------------------------------------------------------------------

typedef float v2f __attribute__((ext_vector_type(2)));

__device__ __forceinline__ float tanh_fast(float x) {
    float e = __expf(2.0f * x);
    return 1.0f - 2.0f / (e + 1.0f);
}

// ---- small-Cin stride-2 conv, thread-per-output, fully unrolled ----
template<int CIN, int COUT, int HIN, int WIN, int HOUT, int WOUT>
__global__ __launch_bounds__(256) void conv_s2_small(
    const float* __restrict__ in, const float* __restrict__ w,
    const float* __restrict__ b, float* __restrict__ out)
{
    int idx = blockIdx.x * 256 + threadIdx.x;
    int wo = idx % WOUT; int t = idx / WOUT;
    int ho = t % HOUT; t /= HOUT;
    int co = t % COUT; int n = t / COUT;
    float acc = b[co];
    int hi0 = ho * 2 - 1, wi0 = wo * 2 - 1;
    const float* wp = w + (size_t)co * CIN * 9;
    #pragma unroll
    for (int ci = 0; ci < CIN; ++ci) {
        const float* ip = in + ((size_t)(n * CIN + ci)) * HIN * WIN;
        const float* wc = wp + ci * 9;
        #pragma unroll
        for (int kh = 0; kh < 3; ++kh) {
            int hi = hi0 + kh;
            if ((unsigned)hi >= (unsigned)HIN) continue;
            const float* row = ip + hi * WIN;
            #pragma unroll
            for (int kw = 0; kw < 3; ++kw) {
                int wi = wi0 + kw;
                if ((unsigned)wi >= (unsigned)WIN) continue;
                acc = fmaf(wc[kh * 3 + kw], row[wi], acc);
            }
        }
    }
    out[idx] = fmaxf(acc, 0.0f);
}

// ---- PARTS-way input-channel-split 3x3 conv; 256 thr = PARTS x OPB outputs.
// threadIdx.x = part*OPB + oidx (oidx fast -> coalesced loads/stores).
template<int CIN, int PARTS, int STRIDE, bool RELU, bool HASB,
         int COUT, int HIN, int WIN, int HOUT, int WOUT>
__device__ __forceinline__ void conv_p_dev(
    const float* __restrict__ in, const float* __restrict__ w,
    const float* __restrict__ b, float* __restrict__ out,
    int tb, float* red)
{
    constexpr int CPT = CIN / PARTS;
    constexpr int OPB = 256 / PARTS;
    int part = threadIdx.x / OPB;
    int oidx = threadIdx.x % OPB;
    int o = tb * OPB + oidx;
    int wo = o % WOUT; int t = o / WOUT;
    int ho = t % HOUT; t /= HOUT;
    int co = t % COUT; int n = t / COUT;
    int hi0 = ho * STRIDE - 1, wi0 = wo * STRIDE - 1;
    const float* wp = w + ((size_t)co * CIN + part * CPT) * 9;
    const float* ip = in + ((size_t)n * CIN + part * CPT) * HIN * WIN;
    float acc = 0.0f;
    #pragma unroll
    for (int ci = 0; ci < CPT; ++ci) {
        const float* ic = ip + (size_t)ci * HIN * WIN;
        const float* wc = wp + ci * 9;
        #pragma unroll
        for (int kh = 0; kh < 3; ++kh) {
            int hi = hi0 + kh;
            if ((unsigned)hi >= (unsigned)HIN) continue;
            const float* row = ic + hi * WIN;
            #pragma unroll
            for (int kw = 0; kw < 3; ++kw) {
                int wi = wi0 + kw;
                if ((unsigned)wi >= (unsigned)WIN) continue;
                acc = fmaf(wc[kh * 3 + kw], row[wi], acc);
            }
        }
    }
    red[threadIdx.x] = acc;
    __syncthreads();
    if (part == 0) {
        float s = acc;
        #pragma unroll
        for (int p = 1; p < PARTS; ++p) s += red[p * OPB + oidx];
        if (HASB) s += b[co];
        if (RELU) s = fmaxf(s, 0.0f);
        out[o] = s;
    }
}

// conv2: t1(4,16,64,64) -> t2(4,32,32,32)
__global__ __launch_bounds__(256) void conv2_k(
    const float* __restrict__ in, const float* __restrict__ w,
    const float* __restrict__ b, float* __restrict__ out)
{
    __shared__ float red[256];
    conv_p_dev<16, 4, 2, true, true, 32, 64, 64, 32, 32>(in, w, b, out, blockIdx.x, red);
}

// conv3: t2 -> splat(4,64,16,16)
__global__ __launch_bounds__(256) void conv3_k(
    const float* __restrict__ in, const float* __restrict__ w,
    const float* __restrict__ b, float* __restrict__ out)
{
    __shared__ float red[256];
    conv_p_dev<32, 8, 2, true, true, 64, 32, 32, 16, 16>(in, w, b, out, blockIdx.x, red);
}

// k5: l0 (splat->l0o, 4096 tbs) + g1 (splat->x1, 2048 tbs)
__global__ __launch_bounds__(256) void k5_l0_g1(
    const float* __restrict__ splat,
    const float* __restrict__ wl0, const float* __restrict__ bl0, float* __restrict__ l0o,
    const float* __restrict__ wg1, const float* __restrict__ bg1, float* __restrict__ x1)
{
    __shared__ float red[256];
    int bid = blockIdx.x;
    if (bid < 4096)
        conv_p_dev<64, 16, 1, true, true, 64, 16, 16, 16, 16>(splat, wl0, bl0, l0o, bid, red);
    else
        conv_p_dev<64, 16, 2, true, true, 128, 16, 16, 8, 8>(splat, wg1, bg1, x1, bid - 4096, red);
}

// k6: l1 (l0o->local, 4096 tbs) + g2 (x1->x2, 1024 tbs) + means(splat), means(x1)
__global__ __launch_bounds__(256) void k6_l1_g2_means(
    const float* __restrict__ l0o, const float* __restrict__ wl1, float* __restrict__ localb,
    const float* __restrict__ x1, const float* __restrict__ wg2,
    const float* __restrict__ bg2, float* __restrict__ x2,
    const float* __restrict__ splat, float* __restrict__ avec)
{
    __shared__ float red[256];
    int bid = blockIdx.x;
    if (bid < 4096) {
        conv_p_dev<64, 16, 1, false, false, 64, 16, 16, 16, 16>(l0o, wl1, nullptr, localb, bid, red);
    } else if (bid < 5120) {
        conv_p_dev<128, 16, 2, true, true, 256, 8, 8, 4, 4>(x1, wg2, bg2, x2, bid - 4096, red);
    } else if (bid < 5184) {
        // splat means: 256 waves, one per (n,c)
        int wid = (bid - 5120) * 4 + (threadIdx.x >> 6);
        int lane = threadIdx.x & 63;
        int n = wid >> 6, c = wid & 63;
        const float* p = splat + ((size_t)(n * 64 + c)) * 256;
        float s = p[lane] + p[lane + 64] + p[lane + 128] + p[lane + 192];
        #pragma unroll
        for (int off = 32; off; off >>= 1) s += __shfl_down(s, off, 64);
        if (lane == 0) avec[n * 448 + c] = s * (1.0f / 256.0f);
    } else {
        // x1 means: 512 waves, one per (n,c)
        int wid = (bid - 5184) * 4 + (threadIdx.x >> 6);
        int lane = threadIdx.x & 63;
        int n = wid >> 7, c = wid & 127;
        const float* p = x1 + ((size_t)(n * 128 + c)) * 64;
        float s = p[lane];
        #pragma unroll
        for (int off = 32; off; off >>= 1) s += __shfl_down(s, off, 64);
        if (lane == 0) avec[n * 448 + 64 + c] = s * (1.0f / 64.0f);
    }
}

// fc chain (with x2 means computed in-block): 448->256->128->64, block per image
__global__ __launch_bounds__(256) void fc_k(
    const float* __restrict__ avec, const float* __restrict__ x2,
    const float* __restrict__ wf1, const float* __restrict__ bf1,
    const float* __restrict__ wf2, const float* __restrict__ bf2,
    const float* __restrict__ wf3, const float* __restrict__ bf3,
    float* __restrict__ glob)
{
    __shared__ float a[448];
    __shared__ float h1[256];
    __shared__ float h2[128];
    int n = blockIdx.x, t = threadIdx.x;
    if (t < 192) a[t] = avec[n * 448 + t];
    {
        const float* p = x2 + ((size_t)(n * 256 + t)) * 16;
        float s = 0.0f;
        #pragma unroll
        for (int i = 0; i < 16; ++i) s += p[i];
        a[192 + t] = s * (1.0f / 16.0f);
    }
    __syncthreads();
    {
        float a0 = 0, a1 = 0, a2 = 0, a3 = 0;
        const float* wp = wf1 + (size_t)t * 448;
        for (int i = 0; i < 448; i += 4) {
            a0 = fmaf(wp[i], a[i], a0); a1 = fmaf(wp[i + 1], a[i + 1], a1);
            a2 = fmaf(wp[i + 2], a[i + 2], a2); a3 = fmaf(wp[i + 3], a[i + 3], a3);
        }
        float s = a0 + a1 + a2 + a3 + bf1[t];
        __syncthreads();
        h1[t] = fmaxf(s, 0.0f);
    }
    __syncthreads();
    if (t < 128) {
        float a0 = 0, a1 = 0, a2 = 0, a3 = 0;
        const float* wp = wf2 + (size_t)t * 256;
        for (int i = 0; i < 256; i += 4) {
            a0 = fmaf(wp[i], h1[i], a0); a1 = fmaf(wp[i + 1], h1[i + 1], a1);
            a2 = fmaf(wp[i + 2], h1[i + 2], a2); a3 = fmaf(wp[i + 3], h1[i + 3], a3);
        }
        h2[t] = fmaxf(a0 + a1 + a2 + a3 + bf2[t], 0.0f);
    }
    __syncthreads();
    if (t < 64) {
        float a0 = 0, a1 = 0, a2 = 0, a3 = 0;
        const float* wp = wf3 + (size_t)t * 128;
        for (int i = 0; i < 128; i += 4) {
            a0 = fmaf(wp[i], h2[i], a0); a1 = fmaf(wp[i + 1], h2[i + 1], a1);
            a2 = fmaf(wp[i + 2], h2[i + 2], a2); a3 = fmaf(wp[i + 3], h2[i + 3], a3);
        }
        glob[n * 64 + t] = fmaxf(a0 + a1 + a2 + a3 + bf3[t], 0.0f);
    }
}

// fuse + 1x1 -> bilateral grid, channel-innermost (n,z,gy,gx,ch)
__global__ __launch_bounds__(256) void fuse_grid(
    const float* __restrict__ glob, const float* __restrict__ local,
    const float* __restrict__ wlin, const float* __restrict__ blin,
    float* __restrict__ grid)
{
    int idx = blockIdx.x * 256 + threadIdx.x;   // 98304
    int p = idx & 255; int k = (idx >> 8) % 96; int n = idx / (96 * 256);
    float acc = blin[k];
    const float* wp = wlin + k * 64;
    const float* gl = glob + n * 64;
    const float* lo = local + (size_t)n * 64 * 256 + p;
    #pragma unroll 8
    for (int c = 0; c < 64; ++c)
        acc = fmaf(wp[c], fmaxf(gl[c] + lo[c * 256], 0.0f), acc);
    int ch = k >> 3; int z = k & 7;
    grid[(((size_t)(n * 8 + z)) * 256 + p) * 12 + ch] = acc;
}

// fused full-res output, 4 px per thread, packed-f32 slice/towers
__global__ __launch_bounds__(256) void hdr_out_v3(
    const float* __restrict__ full, const float* __restrict__ low,
    const float* __restrict__ grid,
    const float* __restrict__ wgd1, const float* __restrict__ bgd1,
    const float* __restrict__ wgd2, const float* __restrict__ bgd2,
    const float* __restrict__ wau1, const float* __restrict__ bau1,
    const float* __restrict__ wau2, const float* __restrict__ bau2,
    const float* __restrict__ wav1, const float* __restrict__ bav1,
    const float* __restrict__ wav2, const float* __restrict__ bav2,
    float* __restrict__ out)
{
    int tid = blockIdx.x * 256 + threadIdx.x;
    int x0 = (tid & 255) << 2;
    int y = (tid >> 8) & 1023;
    int n = tid >> 18;
    const float* fp = full + ((size_t)n << 20);

    float v[3][6];
    #pragma unroll
    for (int r = 0; r < 3; ++r) {
        int yy = y + r - 1;
        bool okr = (unsigned)yy < 1024u;
        const float* row = fp + (size_t)yy * 1024;
        if (okr) {
            float4 m = *(const float4*)(row + x0);
            v[r][1] = m.x; v[r][2] = m.y; v[r][3] = m.z; v[r][4] = m.w;
            v[r][0] = (x0 > 0) ? row[x0 - 1] : 0.0f;
            v[r][5] = (x0 < 1020) ? row[x0 + 4] : 0.0f;
        } else {
            #pragma unroll
            for (int j = 0; j < 6; ++j) v[r][j] = 0.0f;
        }
    }

    float gacc[4];
    float bb = bgd2[0];
    #pragma unroll
    for (int px = 0; px < 4; ++px) gacc[px] = bb;
    #pragma unroll
    for (int k = 0; k < 16; ++k) {
        const float* wk = wgd1 + k * 9;
        float q0 = wk[0], q1 = wk[1], q2 = wk[2];
        float q3 = wk[3], q4 = wk[4], q5 = wk[5];
        float q6 = wk[6], q7 = wk[7], q8 = wk[8];
        float bk = bgd1[k], wo = wgd2[k];
        #pragma unroll
        for (int px = 0; px < 4; ++px) {
            float h = bk;
            h = fmaf(q0, v[0][px], h); h = fmaf(q1, v[0][px + 1], h); h = fmaf(q2, v[0][px + 2], h);
            h = fmaf(q3, v[1][px], h); h = fmaf(q4, v[1][px + 1], h); h = fmaf(q5, v[1][px + 2], h);
            h = fmaf(q6, v[2][px], h); h = fmaf(q7, v[2][px + 1], h); h = fmaf(q8, v[2][px + 2], h);
            gacc[px] = fmaf(wo, fmaxf(h, 0.0f), gacc[px]);
        }
    }

    // y-side slice terms (constant over the 4 px)
    float gyc = (y * (32.0f / 1023.0f) - 1.0f) * 0.5f;
    float y0f = floorf(gyc); float fy = gyc - y0f; int iy = (int)y0f;
    float wy0 = (iy >= 0 && iy < 16) ? (1.0f - fy) : 0.0f;
    float wy1 = (iy + 1 < 16) ? fy : 0.0f;
    int yi0 = min(max(iy, 0), 15), yi1 = min(iy + 1, 15);

    // fake-chroma shared rows/cols
    float sy = (y + 0.5f) * 0.25f - 0.5f;
    float syf = floorf(sy); float fyl = sy - syf;
    int jy0 = max((int)syf, 0), jy1 = min((int)syf + 1, 255);
    int jc = x0 >> 2;
    int c0 = max(jc - 1, 0), c2 = min(jc + 1, 255);
    const float* lr1 = low + ((size_t)(n * 3 + 1)) * 65536;
    const float* lr2 = low + ((size_t)(n * 3 + 2)) * 65536;
    float ua = lr1[jy0 * 256 + c0] + fyl * (lr1[jy1 * 256 + c0] - lr1[jy0 * 256 + c0]);
    float ub = lr1[jy0 * 256 + jc] + fyl * (lr1[jy1 * 256 + jc] - lr1[jy0 * 256 + jc]);
    float uc = lr1[jy0 * 256 + c2] + fyl * (lr1[jy1 * 256 + c2] - lr1[jy0 * 256 + c2]);
    float va = lr2[jy0 * 256 + c0] + fyl * (lr2[jy1 * 256 + c0] - lr2[jy0 * 256 + c0]);
    float vb = lr2[jy0 * 256 + jc] + fyl * (lr2[jy1 * 256 + jc] - lr2[jy0 * 256 + jc]);
    float vc = lr2[jy0 * 256 + c2] + fyl * (lr2[jy1 * 256 + c2] - lr2[jy0 * 256 + c2]);
    const float cfx[4] = {0.625f, 0.875f, 0.125f, 0.375f};

    const float* gbase = grid + (size_t)n * 24576;
    float Yo[4], Uo[4], Vo[4];

    #pragma unroll
    for (int px = 0; px < 4; ++px) {
        int x = x0 + px;
        float g = tanh_fast(gacc[px]);

        float gxc = (x * (32.0f / 1023.0f) - 1.0f) * 0.5f;
        float gzc = 4.0f * g + 3.5f;
        float x0f = floorf(gxc), z0f = floorf(gzc);
        float fx = gxc - x0f, fz = gzc - z0f;
        int ix = (int)x0f, iz = (int)z0f;

        float wx0 = (ix >= 0 && ix < 16) ? (1.0f - fx) : 0.0f;
        float wx1 = (ix + 1 < 16) ? fx : 0.0f;
        float wz0 = (iz >= 0 && iz < 8) ? (1.0f - fz) : 0.0f;
        float wz1 = (iz + 1 >= 0 && iz + 1 < 8) ? fz : 0.0f;
        int xi0 = min(max(ix, 0), 15), xi1 = min(ix + 1, 15);
        int zi0 = min(max(iz, 0), 7),  zi1 = min(max(iz + 1, 0), 7);

        float w00 = wy0 * wx0, w01 = wy0 * wx1, w10 = wy1 * wx0, w11 = wy1 * wx1;
        int o00 = yi0 * 16 + xi0, o01 = yi0 * 16 + xi1;
        int o10 = yi1 * 16 + xi0, o11 = yi1 * 16 + xi1;
        int z0b = zi0 * 256, z1b = zi1 * 256;

        v2f a01 = {0.f, 0.f}, a23 = {0.f, 0.f}, a45 = {0.f, 0.f};
        v2f a67 = {0.f, 0.f}, a89 = {0.f, 0.f}, aAB = {0.f, 0.f};

        #define CORNER(OFF, WK) { \
            const v2f* q = (const v2f*)(gbase + (size_t)(OFF) * 12); \
            float wk_ = (WK); v2f wv = {wk_, wk_}; \
            a01 += wv * q[0]; a23 += wv * q[1]; a45 += wv * q[2]; \
            a67 += wv * q[3]; a89 += wv * q[4]; aAB += wv * q[5]; }

        CORNER(z0b + o00, wz0 * w00)
        CORNER(z0b + o01, wz0 * w01)
        CORNER(z0b + o10, wz0 * w10)
        CORNER(z0b + o11, wz0 * w11)
        CORNER(z1b + o00, wz1 * w00)
        CORNER(z1b + o01, wz1 * w01)
        CORNER(z1b + o10, wz1 * w10)
        CORNER(z1b + o11, wz1 * w11)
        #undef CORNER

        float p = v[1][px + 1];
        float Yv = fmaf(p, a23.y, a01.x + a01.y + a23.x);
        float U0 = fmaf(p, a67.y, a45.x + a45.y + a67.x);
        float V0 = fmaf(p, aAB.y, a89.x + a89.y + aAB.x);

        // packed U/V towers: 1->16 relu ->1, tanh
        v2f uv = {U0, V0};
        v2f acc2 = {bau2[0], bav2[0]};
        #pragma unroll
        for (int k = 0; k < 16; ++k) {
            v2f w1k = {wau1[k], wav1[k]};
            v2f b1k = {bau1[k], bav1[k]};
            v2f w2k = {wau2[k], wav2[k]};
            v2f h = w1k * uv + b1k;
            h.x = fmaxf(h.x, 0.0f); h.y = fmaxf(h.y, 0.0f);
            acc2 += w2k * h;
        }

        float f1 = (px < 2) ? (ua + cfx[px] * (ub - ua)) : (ub + cfx[px] * (uc - ub));
        float f2 = (px < 2) ? (va + cfx[px] * (vb - va)) : (vb + cfx[px] * (vc - vb));

        Yo[px] = Yv;
        Uo[px] = tanh_fast(acc2.x) + f1;
        Vo[px] = tanh_fast(acc2.y) + f2;
    }

    size_t base = ((size_t)n * 3) * 1048576 + (size_t)y * 1024 + x0;
    *(float4*)(out + base)            = make_float4(Yo[0], Yo[1], Yo[2], Yo[3]);
    *(float4*)(out + base + 1048576)  = make_float4(Uo[0], Uo[1], Uo[2], Uo[3]);
    *(float4*)(out + base + 2097152)  = make_float4(Vo[0], Vo[1], Vo[2], Vo[3]);
}

extern "C" void kernel_launch(void* const* d_in, const int* in_sizes, int n_in,
                              void* d_out, int out_size, void* d_ws, size_t ws_size,
                              hipStream_t stream)
{
    const float* low  = (const float*)d_in[0];
    const float* full = (const float*)d_in[1];
    const float* w0 = (const float*)d_in[2];  const float* b0 = (const float*)d_in[3];
    const float* w1 = (const float*)d_in[4];  const float* b1 = (const float*)d_in[5];
    const float* w2 = (const float*)d_in[6];  const float* b2 = (const float*)d_in[7];
    const float* w3 = (const float*)d_in[8];  const float* b3 = (const float*)d_in[9];
    const float* wl0 = (const float*)d_in[10]; const float* bl0 = (const float*)d_in[11];
    const float* wl1 = (const float*)d_in[12];
    const float* wg1 = (const float*)d_in[13]; const float* bg1 = (const float*)d_in[14];
    const float* wg2 = (const float*)d_in[15]; const float* bg2 = (const float*)d_in[16];
    const float* wf1 = (const float*)d_in[17]; const float* bf1 = (const float*)d_in[18];
    const float* wf2 = (const float*)d_in[19]; const float* bf2 = (const float*)d_in[20];
    const float* wf3 = (const float*)d_in[21]; const float* bf3 = (const float*)d_in[22];
    const float* wlin = (const float*)d_in[23]; const float* blin = (const float*)d_in[24];
    const float* wgd1 = (const float*)d_in[25]; const float* bgd1 = (const float*)d_in[26];
    const float* wgd2 = (const float*)d_in[27]; const float* bgd2 = (const float*)d_in[28];
    const float* wau1 = (const float*)d_in[29]; const float* bau1 = (const float*)d_in[30];
    const float* wau2 = (const float*)d_in[31]; const float* bau2 = (const float*)d_in[32];
    const float* wav1 = (const float*)d_in[33]; const float* bav1 = (const float*)d_in[34];
    const float* wav2 = (const float*)d_in[35]; const float* bav2 = (const float*)d_in[36];
    float* out = (float*)d_out;

    float* ws = (float*)d_ws;
    float* t0b    = ws;
    float* t1b    = t0b + 524288;
    float* t2b    = t1b + 262144;
    float* splat  = t2b + 131072;
    float* l0o    = splat + 65536;
    float* localb = l0o + 65536;
    float* x1b    = localb + 65536;
    float* x2b    = x1b + 32768;
    float* avec   = x2b + 16384;
    float* glob   = avec + 1792;
    float* gridb  = glob + 256;

    conv_s2_small<3, 8, 256, 256, 128, 128><<<2048, 256, 0, stream>>>(low, w0, b0, t0b);
    conv_s2_small<8, 16, 128, 128, 64, 64><<<1024, 256, 0, stream>>>(t0b, w1, b1, t1b);
    conv2_k<<<2048, 256, 0, stream>>>(t1b, w2, b2, t2b);
    conv3_k<<<2048, 256, 0, stream>>>(t2b, w3, b3, splat);
    k5_l0_g1<<<6144, 256, 0, stream>>>(splat, wl0, bl0, l0o, wg1, bg1, x1b);
    k6_l1_g2_means<<<5312, 256, 0, stream>>>(l0o, wl1, localb, x1b, wg2, bg2, x2b, splat, avec);
    fc_k<<<4, 256, 0, stream>>>(avec, x2b, wf1, bf1, wf2, bf2, wf3, bf3, glob);
    fuse_grid<<<384, 256, 0, stream>>>(glob, localb, wlin, blin, gridb);
    hdr_out_v3<<<4096, 256, 0, stream>>>(full, low, gridb,
        wgd1, bgd1, wgd2, bgd2, wau1, bau1, wau2, bau2, wav1, bav1, wav2, bav2, out);
}